// Round 12
// baseline (633.259 us; speedup 1.0000x reference)
//
#include <hip/hip_runtime.h>

// StyleConv3D implicit-GEMM on bf16 MFMA (gfx950).
// B=8, Cin=32, Cout=32, D=48, K=3, VALID -> Dout=46.
// R12: R10/R11 single-phase + y-reuse + swizzle (all verified), but tile
//      shrunk to 4z x 4y x 16x -> LDS [36 rows][18 x][ci32] = 41,472 B
//      -> 3 blocks/CU = 6 waves/SIMD (was 2). Wave: 1z x 2y x 16x x 32co,
//      acc 16 VGPR. Per iter: 4 B-frags -> 12 MFMA (3x y-reuse kept).
//      Chip floors: MFMA 23.6us, LDS 19.4us -> latency now hideable by TLP.

typedef unsigned short u16;
typedef __bf16 bf16x8 __attribute__((ext_vector_type(8)));
typedef u16 u16x8 __attribute__((ext_vector_type(8)));
typedef float f32x4 __attribute__((ext_vector_type(4)));

#define XT_BYTES  (8u * 110592u * 32u * 2u)     // 56,623,104
#define WA2_ELEMS (8 * 32 * 27 * 32)            // 221,184 u16 = 442,368 B

__device__ __forceinline__ u16 f2bf(float f) {
    __bf16 h = (__bf16)f;
    return __builtin_bit_cast(u16, h);
}

__device__ __forceinline__ void dma16(const void* g, void* l) {
    __builtin_amdgcn_global_load_lds(
        (const __attribute__((address_space(1))) unsigned*)g,
        (__attribute__((address_space(3))) unsigned*)l, 16, 0, 0);
}

// ------- pre-pass: x f32 -> xT bf16 [b][site][cg4][ci8] -------------------
__global__ __launch_bounds__(256) void xpose_kernel(
    const float* __restrict__ x, u16* __restrict__ xT)
{
    int gid = blockIdx.x * 256 + threadIdx.x;    // 884,736 threads
    int cg   = gid & 3;
    int tmp  = gid >> 2;
    int quad = tmp % 27648;
    int b    = tmp / 27648;
    int site0 = quad * 4;
    const float* xp = x + (size_t)(b * 32 + cg * 8) * 110592 + site0;
    float4 v[8];
#pragma unroll
    for (int j = 0; j < 8; ++j) v[j] = *(const float4*)(xp + (size_t)j * 110592);
#pragma unroll
    for (int k = 0; k < 4; ++k) {
        u16x8 o;
#pragma unroll
        for (int j = 0; j < 8; ++j) o[j] = f2bf(((const float*)&v[j])[k]);
        *(u16x8*)(xT + ((size_t)(b * 110592 + site0 + k) * 4 + cg) * 8) = o;
    }
}

// ------- wnorm: wA2[b][cout][tap27][ci32] ---------------------------------
__global__ __launch_bounds__(64) void wnorm32_kernel(
    const float* __restrict__ s, const float* __restrict__ sw,
    const float* __restrict__ sb, const float* __restrict__ w,
    u16* __restrict__ wA2)
{
    int bc = blockIdx.x;
    int b = bc >> 5, co = bc & 31;
    int lane = threadIdx.x;
    float s0 = s[2 * b], s1 = s[2 * b + 1];

    float sum = 0.f;
    for (int i = lane; i < 864; i += 64) {
        int ci = i / 27;
        float m = fmaf(s0, sw[2 * ci], fmaf(s1, sw[2 * ci + 1], sb[ci]));
        float v = w[co * 864 + i] * m;
        sum += v * v;
    }
#pragma unroll
    for (int off = 32; off; off >>= 1) sum += __shfl_xor(sum, off, 64);
    float rn = 1.0f / sqrtf(sum + 1e-8f);

    for (int i = lane; i < 864; i += 64) {
        int ci = i / 27, tap = i - ci * 27;
        float m = fmaf(s0, sw[2 * ci], fmaf(s1, sw[2 * ci + 1], sb[ci]));
        float v = w[co * 864 + i] * m * rn;
        wA2[((size_t)(b * 32 + co) * 27 + tap) * 32 + ci] = f2bf(v);
    }
}

// ------- conv: single-phase, 3 blocks/CU ----------------------------------
// Block (b, zt, yt, xt3): outputs z0..z0+3, y0..y0+3, x0..x0+15 (mask >=46).
// LDS: [row36][x18][ci32] bf16 = 41,472 B; row = z'*6+y'; swizzled slots.
// 8 waves: zw = w&3, yp = w>>2. Wave: 1z x 2y x 16x x 32co, acc 16 regs.
__global__ __launch_bounds__(512, 6) void conv_one(
    const u16* __restrict__ xT, const u16* __restrict__ wA2,
    const float* __restrict__ bias, float* __restrict__ out)
{
    __shared__ u16 sx[20736];   // 41,472 B

    // XCD-aware bijective swizzle: 3456 = 8 XCD * 432; same b per XCD chunk.
    int orig = blockIdx.x;
    int blk = (orig & 7) * 432 + (orig >> 3);

    int zt = blk % 12, yt = (blk / 12) % 12;
    int rem = blk / 144;                 // 0..23
    int xt3 = rem % 3, b = rem / 3;
    int z0 = zt * 4, y0 = yt * 4, x0 = xt3 * 16;

    int t = threadIdx.x;
    int l = t & 63, w = t >> 6;
    int ln = l & 15;            // MFMA n-col (x) / A m-row (cout)
    int tq = l >> 4;            // k-group: ci = tq*8 + j
    int zw = w & 3, yp = w >> 2;

    // ---- stage: 648 sites x 4 slots = 2592 x 16B DMA, swizzled source ----
    // slot holds ci-group g = slot ^ rot, rot = (row + (x>>1)) & 3
#pragma unroll
    for (int i = 0; i < 6; ++i) {
        int idx = i * 512 + t;
        if (idx < 2592) {
            int site = idx >> 2, slot = idx & 3;
            int row = site / 18, x = site - row * 18;
            int zp = row / 6, yq = row - zp * 6;
            int gz = z0 + zp; if (gz > 47) gz = 47;
            int gy = y0 + yq; if (gy > 47) gy = 47;
            int gx = x0 + x;  if (gx > 47) gx = 47;
            int rot = (row + (x >> 1)) & 3;
            int g = slot ^ rot;
            const u16* src = xT + ((size_t)(b * 110592 + (gz * 48 + gy) * 48 + gx) * 4 + g) * 8;
            dma16(src, (char*)sx + (size_t)idx * 16);
        }
    }
    __syncthreads();   // whole K-tile in LDS; last barrier.

    f32x4 acc[2][2];   // [yr][cout-half]
#pragma unroll
    for (int i = 0; i < 2; i++)
#pragma unroll
        for (int h = 0; h < 2; h++) acc[i][h] = (f32x4)0.f;

    const u16* wAb = wA2 + (size_t)(b * 32) * 27 * 32;
    const u16* aB0 = wAb + (size_t)ln * 864 + tq * 8;          // h=0
    const u16* aB1 = wAb + (size_t)(ln + 16) * 864 + tq * 8;   // h=1

    int pb64[3], ph[3];
#pragma unroll
    for (int dx = 0; dx < 3; ++dx) {
        pb64[dx] = (ln + dx) * 64;
        ph[dx]   = (ln + dx) >> 1;
    }
    int rb = 2 * yp;            // wave y-row base (within 6-row group)

    u16x8 Bf[2][4];             // ping-pong: 4 y-rows
    u16x8 Af[2][3][2];

#define PFI(ii, buf) { \
    const int dz_ = (ii) / 3, dx_ = (ii) % 3; \
    _Pragma("unroll") \
    for (int r = 0; r < 4; ++r) { \
        int rowi = (zw + dz_) * 6 + rb + r; \
        int rot = (rowi + ph[dx_]) & 3; \
        int so = rowi * 1152 + pb64[dx_] + ((tq ^ rot) << 4); \
        Bf[buf][r] = *(const u16x8*)((const char*)sx + so); \
    } \
    _Pragma("unroll") \
    for (int dy = 0; dy < 3; ++dy) { \
        const int tap_ = (dz_ * 3 + dy) * 3 + dx_; \
        Af[buf][dy][0] = *(const u16x8*)(aB0 + tap_ * 32); \
        Af[buf][dy][1] = *(const u16x8*)(aB1 + tap_ * 32); \
    } }

#define CMI(buf) { \
    _Pragma("unroll") \
    for (int dy = 0; dy < 3; ++dy) \
        _Pragma("unroll") \
        for (int yr = 0; yr < 2; ++yr) \
            _Pragma("unroll") \
            for (int h = 0; h < 2; ++h) \
                acc[yr][h] = __builtin_amdgcn_mfma_f32_16x16x32_bf16( \
                    __builtin_bit_cast(bf16x8, Af[buf][dy][h]), \
                    __builtin_bit_cast(bf16x8, Bf[buf][yr + dy]), \
                    acc[yr][h], 0, 0, 0); }

    PFI(0, 0)
#pragma unroll
    for (int i = 0; i < 9; ++i) {
        if (i < 8) {
            const int nb = (i + 1) & 1;
            switch (i + 1) {
                case 1: PFI(1, nb) break;
                case 2: PFI(2, nb) break;
                case 3: PFI(3, nb) break;
                case 4: PFI(4, nb) break;
                case 5: PFI(5, nb) break;
                case 6: PFI(6, nb) break;
                case 7: PFI(7, nb) break;
                case 8: PFI(8, nb) break;
            }
        }
        __builtin_amdgcn_sched_barrier(0);
        const int cb = i & 1;
        CMI(cb)
        __builtin_amdgcn_sched_barrier(0);
    }
#undef PFI
#undef CMI

    // ---- store: C layout col=lane&15 (x), row=(lane>>4)*4+reg (cout) ----
    int oz = z0 + zw;
    int ox = x0 + ln;
    if (oz < 46 && ox < 46) {
#pragma unroll
        for (int yr = 0; yr < 2; ++yr) {
            int oy = y0 + 2 * yp + yr;
            if (oy >= 46) continue;
#pragma unroll
            for (int h = 0; h < 2; ++h) {
                f32x4 a = acc[yr][h];
#pragma unroll
                for (int r = 0; r < 4; ++r) {
                    int co = h * 16 + tq * 4 + r;
                    out[(size_t)(b * 32 + co) * 97336 + oz * 2116 + oy * 46 + ox]
                        = a[r] + bias[co];
                }
            }
        }
    }
}

// ================= fallback path (R2, proven) ============================
__global__ __launch_bounds__(64) void wnorm16_kernel(
    const float* __restrict__ s, const float* __restrict__ sw,
    const float* __restrict__ sb, const float* __restrict__ w,
    u16* __restrict__ wA)          // [b][chunk2][cout][tap28][ci16]
{
    int bc = blockIdx.x;
    int b = bc >> 5, co = bc & 31;
    int lane = threadIdx.x;
    float s0 = s[2 * b], s1 = s[2 * b + 1];

    float sum = 0.f;
    for (int i = lane; i < 864; i += 64) {
        int ci = i / 27;
        float m = fmaf(s0, sw[2 * ci], fmaf(s1, sw[2 * ci + 1], sb[ci]));
        float v = w[co * 864 + i] * m;
        sum += v * v;
    }
#pragma unroll
    for (int off = 32; off; off >>= 1) sum += __shfl_xor(sum, off, 64);
    float rn = 1.0f / sqrtf(sum + 1e-8f);

    for (int i = lane; i < 864; i += 64) {
        int ci = i / 27, tap = i - ci * 27;
        float m = fmaf(s0, sw[2 * ci], fmaf(s1, sw[2 * ci + 1], sb[ci]));
        float v = w[co * 864 + i] * m * rn;
        int chunk = ci >> 4, ci16 = ci & 15;
        wA[(((b * 2 + chunk) * 32 + co) * 28 + tap) * 16 + ci16] = f2bf(v);
    }
    if (lane < 32) {
        int c = lane >> 4, ci16 = lane & 15;
        wA[(((b * 2 + c) * 32 + co) * 28 + 27) * 16 + ci16] = 0;
    }
}

__global__ __launch_bounds__(512) void conv_fallback(
    const float* __restrict__ xin, const u16* __restrict__ wA,
    const float* __restrict__ bias, float* __restrict__ out)
{
    __shared__ u16 sx[28800];

    int blk = blockIdx.x;
    int zt = blk % 12, yt = (blk / 12) % 12, b = blk / 144;
    int z0 = zt * 4, y0 = yt * 4;

    int t = threadIdx.x;
    int l = t & 63, w = t >> 6;
    int ln = l & 15, ch = (l >> 4) & 1, tp = l >> 5, rg = l >> 4;
    int zw = w & 3, yp = w >> 2;

    f32x4 acc[2][3][2];
#pragma unroll
    for (int i = 0; i < 2; i++)
#pragma unroll
        for (int j = 0; j < 3; j++)
#pragma unroll
            for (int h = 0; h < 2; h++) acc[i][j][h] = (f32x4)0.f;

    for (int chunk = 0; chunk < 2; ++chunk) {
        __syncthreads();
        for (int idx = t; idx < 3600; idx += 512) {
            int x = idx % 50;
            int r = idx / 50;
            int cg = r & 1; r >>= 1;
            int y = r % 6, z = r / 6;
            int gz = z0 + z, gy = y0 + y;
            bool inb = (x < 48) && (gy < 48) && (gz < 48);
            const float* xp = xin + (size_t)(b * 32 + chunk * 16 + cg * 8) * 110592
                              + gz * 2304 + gy * 48 + x;
            u16x8 v;
#pragma unroll
            for (int j = 0; j < 8; j++) {
                float f = inb ? xp[(size_t)j * 110592] : 0.f;
                v[j] = f2bf(f);
            }
            *(u16x8*)&sx[idx * 8] = v;
        }
        __syncthreads();

        const u16* wAc = wA + (b * 2 + chunk) * (32 * 28 * 16);
        int aoff = (ln * 28 + tp) * 16 + ch * 8;

#pragma unroll
        for (int s = 0; s < 14; ++s) {
            int tapA = 2 * s + tp;
            bf16x8 A0 = __builtin_bit_cast(bf16x8, *(const u16x8*)(wAc + aoff + s * 32));
            bf16x8 A1 = __builtin_bit_cast(bf16x8, *(const u16x8*)(wAc + aoff + 16 * 28 * 16 + s * 32));
            int tapB = tapA > 26 ? 26 : tapA;
            int dz = tapB / 9;
            int rr = tapB - dz * 9;
            int dy = rr / 3;
            int dx = rr - dy * 3;
            int zr = zw + dz;
#pragma unroll
            for (int yr = 0; yr < 2; ++yr) {
                int yy = 2 * yp + yr + dy;
                int eb = (((zr * 6 + yy) * 2 + ch) * 50 + ln + dx) * 8;
#pragma unroll
                for (int xt = 0; xt < 3; ++xt) {
                    bf16x8 Bf2 = __builtin_bit_cast(bf16x8, *(const u16x8*)&sx[eb + xt * 128]);
                    acc[yr][xt][0] = __builtin_amdgcn_mfma_f32_16x16x32_bf16(A0, Bf2, acc[yr][xt][0], 0, 0, 0);
                    acc[yr][xt][1] = __builtin_amdgcn_mfma_f32_16x16x32_bf16(A1, Bf2, acc[yr][xt][1], 0, 0, 0);
                }
            }
        }
    }

    int oz = z0 + zw;
    if (oz < 46) {
#pragma unroll
        for (int yr = 0; yr < 2; ++yr) {
            int oy = y0 + 2 * yp + yr;
            if (oy >= 46) continue;
#pragma unroll
            for (int xt = 0; xt < 3; ++xt) {
                int ox = xt * 16 + ln;
                if (ox >= 46) continue;
#pragma unroll
                for (int h = 0; h < 2; ++h) {
                    f32x4 a = acc[yr][xt][h];
#pragma unroll
                    for (int r = 0; r < 4; ++r) {
                        int co = h * 16 + rg * 4 + r;
                        out[(size_t)(b * 32 + co) * 97336 + oz * 2116 + oy * 46 + ox]
                            = a[r] + bias[co];
                    }
                }
            }
        }
    }
}

extern "C" void kernel_launch(void* const* d_in, const int* in_sizes, int n_in,
                              void* d_out, int out_size, void* d_ws, size_t ws_size,
                              hipStream_t stream) {
    const float* x    = (const float*)d_in[0];
    const float* s    = (const float*)d_in[1];
    const float* sw   = (const float*)d_in[2];
    const float* sb   = (const float*)d_in[3];
    const float* wgt  = (const float*)d_in[4];
    const float* bias = (const float*)d_in[5];
    float* out = (float*)d_out;

    const size_t need = (size_t)XT_BYTES + WA2_ELEMS * sizeof(u16);
    if (ws_size >= need) {
        u16* xT  = (u16*)d_ws;
        u16* wA2 = (u16*)((char*)d_ws + XT_BYTES);
        hipLaunchKernelGGL(xpose_kernel, dim3(3456), dim3(256), 0, stream, x, xT);
        hipLaunchKernelGGL(wnorm32_kernel, dim3(256), dim3(64), 0, stream,
                           s, sw, sb, wgt, wA2);
        hipLaunchKernelGGL(conv_one, dim3(3456), dim3(512), 0, stream,
                           xT, wA2, bias, out);
    } else {
        u16* wA = (u16*)d_ws;
        hipLaunchKernelGGL(wnorm16_kernel, dim3(256), dim3(64), 0, stream,
                           s, sw, sb, wgt, wA);
        hipLaunchKernelGGL(conv_fallback, dim3(12 * 12 * 8), dim3(512), 0, stream,
                           x, wA, bias, out);
    }
}

// Round 13
// 156.264 us; speedup vs baseline: 4.0525x; 4.0525x over previous
//
#include <hip/hip_runtime.h>

// StyleConv3D implicit-GEMM on bf16 MFMA (gfx950).
// B=8, Cin=32, Cout=32, D=48, K=3, VALID -> Dout=46.
// R13: R12 geometry (4z x 4y x 16x tile, LDS 41.5 KB -> 3 blocks/CU,
//      6 waves/SIMD) WITHOUT the ping-pong fragment sets. R12 spilled:
//      (512,6) caps VGPR at ~85 but ping-pong needed ~116 -> 1.5 GB
//      scratch traffic. Per-iter regs now ~76: acc 16 + Bf 16 + Af 24 +
//      addr ~20. TLP (6 waves/SIMD) replaces ILP for latency hiding.

typedef unsigned short u16;
typedef __bf16 bf16x8 __attribute__((ext_vector_type(8)));
typedef u16 u16x8 __attribute__((ext_vector_type(8)));
typedef float f32x4 __attribute__((ext_vector_type(4)));

#define XT_BYTES  (8u * 110592u * 32u * 2u)     // 56,623,104
#define WA2_ELEMS (8 * 32 * 27 * 32)            // 221,184 u16 = 442,368 B

__device__ __forceinline__ u16 f2bf(float f) {
    __bf16 h = (__bf16)f;
    return __builtin_bit_cast(u16, h);
}

__device__ __forceinline__ void dma16(const void* g, void* l) {
    __builtin_amdgcn_global_load_lds(
        (const __attribute__((address_space(1))) unsigned*)g,
        (__attribute__((address_space(3))) unsigned*)l, 16, 0, 0);
}

// ------- pre-pass: x f32 -> xT bf16 [b][site][cg4][ci8] -------------------
__global__ __launch_bounds__(256) void xpose_kernel(
    const float* __restrict__ x, u16* __restrict__ xT)
{
    int gid = blockIdx.x * 256 + threadIdx.x;    // 884,736 threads
    int cg   = gid & 3;
    int tmp  = gid >> 2;
    int quad = tmp % 27648;
    int b    = tmp / 27648;
    int site0 = quad * 4;
    const float* xp = x + (size_t)(b * 32 + cg * 8) * 110592 + site0;
    float4 v[8];
#pragma unroll
    for (int j = 0; j < 8; ++j) v[j] = *(const float4*)(xp + (size_t)j * 110592);
#pragma unroll
    for (int k = 0; k < 4; ++k) {
        u16x8 o;
#pragma unroll
        for (int j = 0; j < 8; ++j) o[j] = f2bf(((const float*)&v[j])[k]);
        *(u16x8*)(xT + ((size_t)(b * 110592 + site0 + k) * 4 + cg) * 8) = o;
    }
}

// ------- wnorm: wA2[b][cout][tap27][ci32] ---------------------------------
__global__ __launch_bounds__(64) void wnorm32_kernel(
    const float* __restrict__ s, const float* __restrict__ sw,
    const float* __restrict__ sb, const float* __restrict__ w,
    u16* __restrict__ wA2)
{
    int bc = blockIdx.x;
    int b = bc >> 5, co = bc & 31;
    int lane = threadIdx.x;
    float s0 = s[2 * b], s1 = s[2 * b + 1];

    float sum = 0.f;
    for (int i = lane; i < 864; i += 64) {
        int ci = i / 27;
        float m = fmaf(s0, sw[2 * ci], fmaf(s1, sw[2 * ci + 1], sb[ci]));
        float v = w[co * 864 + i] * m;
        sum += v * v;
    }
#pragma unroll
    for (int off = 32; off; off >>= 1) sum += __shfl_xor(sum, off, 64);
    float rn = 1.0f / sqrtf(sum + 1e-8f);

    for (int i = lane; i < 864; i += 64) {
        int ci = i / 27, tap = i - ci * 27;
        float m = fmaf(s0, sw[2 * ci], fmaf(s1, sw[2 * ci + 1], sb[ci]));
        float v = w[co * 864 + i] * m * rn;
        wA2[((size_t)(b * 32 + co) * 27 + tap) * 32 + ci] = f2bf(v);
    }
}

// ------- conv: single-phase, 3 blocks/CU, no explicit pipeline ------------
// Block (b, zt, yt, xt3): outputs z0..z0+3, y0..y0+3, x0..x0+15 (mask >=46).
// LDS: [row36][x18][ci32] bf16 = 41,472 B; row = z'*6+y'; swizzled slots.
// 8 waves: zw = w&3, yp = w>>2. Wave: 1z x 2y x 16x x 32co, acc 16 regs.
__global__ __launch_bounds__(512, 6) void conv_one(
    const u16* __restrict__ xT, const u16* __restrict__ wA2,
    const float* __restrict__ bias, float* __restrict__ out)
{
    __shared__ u16 sx[20736];   // 41,472 B

    // XCD-aware bijective swizzle: 3456 = 8 XCD * 432; same b per XCD chunk.
    int orig = blockIdx.x;
    int blk = (orig & 7) * 432 + (orig >> 3);

    int zt = blk % 12, yt = (blk / 12) % 12;
    int rem = blk / 144;                 // 0..23
    int xt3 = rem % 3, b = rem / 3;
    int z0 = zt * 4, y0 = yt * 4, x0 = xt3 * 16;

    int t = threadIdx.x;
    int l = t & 63, w = t >> 6;
    int ln = l & 15;            // MFMA n-col (x) / A m-row (cout)
    int tq = l >> 4;            // k-group: ci = tq*8 + j
    int zw = w & 3, yp = w >> 2;

    // ---- stage: 648 sites x 4 slots = 2592 x 16B DMA, swizzled source ----
    // slot holds ci-group g = slot ^ rot, rot = (row + (x>>1)) & 3
#pragma unroll
    for (int i = 0; i < 6; ++i) {
        int idx = i * 512 + t;
        if (idx < 2592) {
            int site = idx >> 2, slot = idx & 3;
            int row = site / 18, x = site - row * 18;
            int zp = row / 6, yq = row - zp * 6;
            int gz = z0 + zp; if (gz > 47) gz = 47;
            int gy = y0 + yq; if (gy > 47) gy = 47;
            int gx = x0 + x;  if (gx > 47) gx = 47;
            int rot = (row + (x >> 1)) & 3;
            int g = slot ^ rot;
            const u16* src = xT + ((size_t)(b * 110592 + (gz * 48 + gy) * 48 + gx) * 4 + g) * 8;
            dma16(src, (char*)sx + (size_t)idx * 16);
        }
    }
    __syncthreads();   // whole K-tile in LDS; last barrier.

    f32x4 acc[2][2];   // [yr][cout-half]
#pragma unroll
    for (int i = 0; i < 2; i++)
#pragma unroll
        for (int h = 0; h < 2; h++) acc[i][h] = (f32x4)0.f;

    const u16* wAb = wA2 + (size_t)(b * 32) * 27 * 32;
    const u16* aB0 = wAb + (size_t)ln * 864 + tq * 8;          // h=0
    const u16* aB1 = wAb + (size_t)(ln + 16) * 864 + tq * 8;   // h=1

    int pb64[3], ph[3];
#pragma unroll
    for (int dx = 0; dx < 3; ++dx) {
        pb64[dx] = (ln + dx) * 64;
        ph[dx]   = (ln + dx) >> 1;
    }
    int rb = 2 * yp;            // wave y-row base (within 6-row group)

#pragma unroll
    for (int dz = 0; dz < 3; ++dz) {
#pragma unroll
        for (int dx = 0; dx < 3; ++dx) {
            // ---- 4 B-frags (y-rows) ----
            u16x8 Bf[4];
#pragma unroll
            for (int r = 0; r < 4; ++r) {
                int rowi = (zw + dz) * 6 + rb + r;
                int rot = (rowi + ph[dx]) & 3;
                int so = rowi * 1152 + pb64[dx] + ((tq ^ rot) << 4);
                Bf[r] = *(const u16x8*)((const char*)sx + so);
            }
            // ---- 6 A-frags (dy x couthalf) ----
            u16x8 Af[3][2];
#pragma unroll
            for (int dy = 0; dy < 3; ++dy) {
                const int tap = (dz * 3 + dy) * 3 + dx;
                Af[dy][0] = *(const u16x8*)(aB0 + tap * 32);
                Af[dy][1] = *(const u16x8*)(aB1 + tap * 32);
            }
            // ---- 12 MFMAs: acc[yr] += A(dy) * B[rb + yr + dy] ----
#pragma unroll
            for (int dy = 0; dy < 3; ++dy)
#pragma unroll
                for (int yr = 0; yr < 2; ++yr)
#pragma unroll
                    for (int h = 0; h < 2; ++h)
                        acc[yr][h] = __builtin_amdgcn_mfma_f32_16x16x32_bf16(
                            __builtin_bit_cast(bf16x8, Af[dy][h]),
                            __builtin_bit_cast(bf16x8, Bf[yr + dy]),
                            acc[yr][h], 0, 0, 0);
        }
    }

    // ---- store: C layout col=lane&15 (x), row=(lane>>4)*4+reg (cout) ----
    int oz = z0 + zw;
    int ox = x0 + ln;
    if (oz < 46 && ox < 46) {
#pragma unroll
        for (int yr = 0; yr < 2; ++yr) {
            int oy = y0 + 2 * yp + yr;
            if (oy >= 46) continue;
#pragma unroll
            for (int h = 0; h < 2; ++h) {
                f32x4 a = acc[yr][h];
#pragma unroll
                for (int r = 0; r < 4; ++r) {
                    int co = h * 16 + tq * 4 + r;
                    out[(size_t)(b * 32 + co) * 97336 + oz * 2116 + oy * 46 + ox]
                        = a[r] + bias[co];
                }
            }
        }
    }
}

// ================= fallback path (R2, proven) ============================
__global__ __launch_bounds__(64) void wnorm16_kernel(
    const float* __restrict__ s, const float* __restrict__ sw,
    const float* __restrict__ sb, const float* __restrict__ w,
    u16* __restrict__ wA)          // [b][chunk2][cout][tap28][ci16]
{
    int bc = blockIdx.x;
    int b = bc >> 5, co = bc & 31;
    int lane = threadIdx.x;
    float s0 = s[2 * b], s1 = s[2 * b + 1];

    float sum = 0.f;
    for (int i = lane; i < 864; i += 64) {
        int ci = i / 27;
        float m = fmaf(s0, sw[2 * ci], fmaf(s1, sw[2 * ci + 1], sb[ci]));
        float v = w[co * 864 + i] * m;
        sum += v * v;
    }
#pragma unroll
    for (int off = 32; off; off >>= 1) sum += __shfl_xor(sum, off, 64);
    float rn = 1.0f / sqrtf(sum + 1e-8f);

    for (int i = lane; i < 864; i += 64) {
        int ci = i / 27, tap = i - ci * 27;
        float m = fmaf(s0, sw[2 * ci], fmaf(s1, sw[2 * ci + 1], sb[ci]));
        float v = w[co * 864 + i] * m * rn;
        int chunk = ci >> 4, ci16 = ci & 15;
        wA[(((b * 2 + chunk) * 32 + co) * 28 + tap) * 16 + ci16] = f2bf(v);
    }
    if (lane < 32) {
        int c = lane >> 4, ci16 = lane & 15;
        wA[(((b * 2 + c) * 32 + co) * 28 + 27) * 16 + ci16] = 0;
    }
}

__global__ __launch_bounds__(512) void conv_fallback(
    const float* __restrict__ xin, const u16* __restrict__ wA,
    const float* __restrict__ bias, float* __restrict__ out)
{
    __shared__ u16 sx[28800];

    int blk = blockIdx.x;
    int zt = blk % 12, yt = (blk / 12) % 12, b = blk / 144;
    int z0 = zt * 4, y0 = yt * 4;

    int t = threadIdx.x;
    int l = t & 63, w = t >> 6;
    int ln = l & 15, ch = (l >> 4) & 1, tp = l >> 5, rg = l >> 4;
    int zw = w & 3, yp = w >> 2;

    f32x4 acc[2][3][2];
#pragma unroll
    for (int i = 0; i < 2; i++)
#pragma unroll
        for (int j = 0; j < 3; j++)
#pragma unroll
            for (int h = 0; h < 2; h++) acc[i][j][h] = (f32x4)0.f;

    for (int chunk = 0; chunk < 2; ++chunk) {
        __syncthreads();
        for (int idx = t; idx < 3600; idx += 512) {
            int x = idx % 50;
            int r = idx / 50;
            int cg = r & 1; r >>= 1;
            int y = r % 6, z = r / 6;
            int gz = z0 + z, gy = y0 + y;
            bool inb = (x < 48) && (gy < 48) && (gz < 48);
            const float* xp = xin + (size_t)(b * 32 + chunk * 16 + cg * 8) * 110592
                              + gz * 2304 + gy * 48 + x;
            u16x8 v;
#pragma unroll
            for (int j = 0; j < 8; j++) {
                float f = inb ? xp[(size_t)j * 110592] : 0.f;
                v[j] = f2bf(f);
            }
            *(u16x8*)&sx[idx * 8] = v;
        }
        __syncthreads();

        const u16* wAc = wA + (b * 2 + chunk) * (32 * 28 * 16);
        int aoff = (ln * 28 + tp) * 16 + ch * 8;

#pragma unroll
        for (int s = 0; s < 14; ++s) {
            int tapA = 2 * s + tp;
            bf16x8 A0 = __builtin_bit_cast(bf16x8, *(const u16x8*)(wAc + aoff + s * 32));
            bf16x8 A1 = __builtin_bit_cast(bf16x8, *(const u16x8*)(wAc + aoff + 16 * 28 * 16 + s * 32));
            int tapB = tapA > 26 ? 26 : tapA;
            int dz = tapB / 9;
            int rr = tapB - dz * 9;
            int dy = rr / 3;
            int dx = rr - dy * 3;
            int zr = zw + dz;
#pragma unroll
            for (int yr = 0; yr < 2; ++yr) {
                int yy = 2 * yp + yr + dy;
                int eb = (((zr * 6 + yy) * 2 + ch) * 50 + ln + dx) * 8;
#pragma unroll
                for (int xt = 0; xt < 3; ++xt) {
                    bf16x8 Bf2 = __builtin_bit_cast(bf16x8, *(const u16x8*)&sx[eb + xt * 128]);
                    acc[yr][xt][0] = __builtin_amdgcn_mfma_f32_16x16x32_bf16(A0, Bf2, acc[yr][xt][0], 0, 0, 0);
                    acc[yr][xt][1] = __builtin_amdgcn_mfma_f32_16x16x32_bf16(A1, Bf2, acc[yr][xt][1], 0, 0, 0);
                }
            }
        }
    }

    int oz = z0 + zw;
    if (oz < 46) {
#pragma unroll
        for (int yr = 0; yr < 2; ++yr) {
            int oy = y0 + 2 * yp + yr;
            if (oy >= 46) continue;
#pragma unroll
            for (int xt = 0; xt < 3; ++xt) {
                int ox = xt * 16 + ln;
                if (ox >= 46) continue;
#pragma unroll
                for (int h = 0; h < 2; ++h) {
                    f32x4 a = acc[yr][xt][h];
#pragma unroll
                    for (int r = 0; r < 4; ++r) {
                        int co = h * 16 + rg * 4 + r;
                        out[(size_t)(b * 32 + co) * 97336 + oz * 2116 + oy * 46 + ox]
                            = a[r] + bias[co];
                    }
                }
            }
        }
    }
}

extern "C" void kernel_launch(void* const* d_in, const int* in_sizes, int n_in,
                              void* d_out, int out_size, void* d_ws, size_t ws_size,
                              hipStream_t stream) {
    const float* x    = (const float*)d_in[0];
    const float* s    = (const float*)d_in[1];
    const float* sw   = (const float*)d_in[2];
    const float* sb   = (const float*)d_in[3];
    const float* wgt  = (const float*)d_in[4];
    const float* bias = (const float*)d_in[5];
    float* out = (float*)d_out;

    const size_t need = (size_t)XT_BYTES + WA2_ELEMS * sizeof(u16);
    if (ws_size >= need) {
        u16* xT  = (u16*)d_ws;
        u16* wA2 = (u16*)((char*)d_ws + XT_BYTES);
        hipLaunchKernelGGL(xpose_kernel, dim3(3456), dim3(256), 0, stream, x, xT);
        hipLaunchKernelGGL(wnorm32_kernel, dim3(256), dim3(64), 0, stream,
                           s, sw, sb, wgt, wA2);
        hipLaunchKernelGGL(conv_one, dim3(3456), dim3(512), 0, stream,
                           xT, wA2, bias, out);
    } else {
        u16* wA = (u16*)d_ws;
        hipLaunchKernelGGL(wnorm16_kernel, dim3(256), dim3(64), 0, stream,
                           s, sw, sb, wgt, wA);
        hipLaunchKernelGGL(conv_fallback, dim3(12 * 12 * 8), dim3(512), 0, stream,
                           x, wA, bias, out);
    }
}

// Round 14
// 109.066 us; speedup vs baseline: 5.8062x; 1.4327x over previous
//
#include <hip/hip_runtime.h>

// StyleConv3D implicit-GEMM on bf16 MFMA (gfx950).
// B=8, Cin=32, Cout=32, D=48, K=3, VALID -> Dout=46.
// R14: R11 single-phase structure (115 KB LDS, y-reuse, swizzle, 1 blk/CU)
//      + inline-asm volatile ds_read_b128 B-fragment pipeline. The compiler
//      sank every C-level ping-pong (R5/R7/R11: VGPR 56-112); asm volatile
//      cannot be sunk. Per iter: issue 12 asm ds_reads for i+1, A-loads for
//      i+1, then s_waitcnt lgkmcnt(12) + sched_barrier(0) (rule #18), then
//      36 MFMAs of iter i. (512,2) -> 256 VGPR cap, budget ~222. No
//      barriers in the loop.

typedef unsigned short u16;
typedef __bf16 bf16x8 __attribute__((ext_vector_type(8)));
typedef u16 u16x8 __attribute__((ext_vector_type(8)));
typedef float f32x4 __attribute__((ext_vector_type(4)));

#define XT_BYTES  (8u * 110592u * 32u * 2u)     // 56,623,104
#define WA2_ELEMS (8 * 32 * 27 * 32)            // 221,184 u16 = 442,368 B

__device__ __forceinline__ u16 f2bf(float f) {
    __bf16 h = (__bf16)f;
    return __builtin_bit_cast(u16, h);
}

__device__ __forceinline__ void dma16(const void* g, void* l) {
    __builtin_amdgcn_global_load_lds(
        (const __attribute__((address_space(1))) unsigned*)g,
        (__attribute__((address_space(3))) unsigned*)l, 16, 0, 0);
}

__device__ __forceinline__ unsigned ldsoff(const void* p) {
    return (unsigned)(size_t)(const __attribute__((address_space(3))) char*)p;
}

// ------- pre-pass: x f32 -> xT bf16 [b][site][cg4][ci8] -------------------
__global__ __launch_bounds__(256) void xpose_kernel(
    const float* __restrict__ x, u16* __restrict__ xT)
{
    int gid = blockIdx.x * 256 + threadIdx.x;    // 884,736 threads
    int cg   = gid & 3;
    int tmp  = gid >> 2;
    int quad = tmp % 27648;
    int b    = tmp / 27648;
    int site0 = quad * 4;
    const float* xp = x + (size_t)(b * 32 + cg * 8) * 110592 + site0;
    float4 v[8];
#pragma unroll
    for (int j = 0; j < 8; ++j) v[j] = *(const float4*)(xp + (size_t)j * 110592);
#pragma unroll
    for (int k = 0; k < 4; ++k) {
        u16x8 o;
#pragma unroll
        for (int j = 0; j < 8; ++j) o[j] = f2bf(((const float*)&v[j])[k]);
        *(u16x8*)(xT + ((size_t)(b * 110592 + site0 + k) * 4 + cg) * 8) = o;
    }
}

// ------- wnorm: wA2[b][cout][tap27][ci32] ---------------------------------
__global__ __launch_bounds__(64) void wnorm32_kernel(
    const float* __restrict__ s, const float* __restrict__ sw,
    const float* __restrict__ sb, const float* __restrict__ w,
    u16* __restrict__ wA2)
{
    int bc = blockIdx.x;
    int b = bc >> 5, co = bc & 31;
    int lane = threadIdx.x;
    float s0 = s[2 * b], s1 = s[2 * b + 1];

    float sum = 0.f;
    for (int i = lane; i < 864; i += 64) {
        int ci = i / 27;
        float m = fmaf(s0, sw[2 * ci], fmaf(s1, sw[2 * ci + 1], sb[ci]));
        float v = w[co * 864 + i] * m;
        sum += v * v;
    }
#pragma unroll
    for (int off = 32; off; off >>= 1) sum += __shfl_xor(sum, off, 64);
    float rn = 1.0f / sqrtf(sum + 1e-8f);

    for (int i = lane; i < 864; i += 64) {
        int ci = i / 27, tap = i - ci * 27;
        float m = fmaf(s0, sw[2 * ci], fmaf(s1, sw[2 * ci + 1], sb[ci]));
        float v = w[co * 864 + i] * m * rn;
        wA2[((size_t)(b * 32 + co) * 27 + tap) * 32 + ci] = f2bf(v);
    }
}

// ------- conv: single-phase, asm-pipelined tap loop -----------------------
// Block (b, zt, yt): outputs z0..z0+3, y0..y0+3, x 0..47 (mask >=46).
// LDS: [row36][x50][ci32] bf16 = 115,200 B, row = z'*6+y', swizzled slots.
// 8 waves: w -> (zw = w&3, yp = (w>>2)&1). Wave: 1z x 2y x 48x x 32co.
__global__ __launch_bounds__(512, 2) void conv_one(
    const u16* __restrict__ xT, const u16* __restrict__ wA2,
    const float* __restrict__ bias, float* __restrict__ out)
{
    __shared__ u16 sx[57600];   // 115,200 B

    // XCD-aware bijective swizzle: 1152 = 8 XCD * 144; each XCD gets one b.
    int orig = blockIdx.x;
    int blk = (orig & 7) * 144 + (orig >> 3);

    int zt = blk % 12, yt = (blk / 12) % 12, b = blk / 144;
    int z0 = zt * 4, y0 = yt * 4;

    int t = threadIdx.x;
    int l = t & 63, w = t >> 6;
    int ln = l & 15;            // MFMA n-col (x) / A m-row (cout)
    int tq = l >> 4;            // k-group: ci = tq*8 + j
    int zw = w & 3, yp = (w >> 2) & 1;

    // ---- stage: 1800 sites x 4 slots = 7200 x 16B DMA, swizzled source ----
#pragma unroll
    for (int i = 0; i < 15; ++i) {
        int idx = i * 512 + t;
        if (idx < 7200) {
            int site = idx >> 2, slot = idx & 3;
            int row = site / 50, x = site - row * 50;
            int zp = row / 6, yq = row - zp * 6;
            int gz = z0 + zp; if (gz > 47) gz = 47;
            int gy = y0 + yq; if (gy > 47) gy = 47;
            int gx = x > 47 ? 47 : x;
            int rot = (row + (x >> 1)) & 3;
            int g = slot ^ rot;
            const u16* src = xT + ((size_t)(b * 110592 + (gz * 48 + gy) * 48 + gx) * 4 + g) * 8;
            dma16(src, (char*)sx + (size_t)idx * 16);
        }
    }
    __syncthreads();   // whole K-tile in LDS; last barrier.

    f32x4 acc[2][3][2];
#pragma unroll
    for (int i = 0; i < 2; i++)
#pragma unroll
        for (int j = 0; j < 3; j++)
#pragma unroll
            for (int h = 0; h < 2; h++) acc[i][j][h] = (f32x4)0.f;

    const u16* wAb = wA2 + (size_t)(b * 32) * 27 * 32;
    const u16* aB0 = wAb + (size_t)ln * 864 + tq * 8;          // h=0
    const u16* aB1 = wAb + (size_t)(ln + 16) * 864 + tq * 8;   // h=1

    int pb64[3], ph[3];
#pragma unroll
    for (int dx = 0; dx < 3; ++dx) {
        pb64[dx] = (ln + dx) * 64;
        ph[dx]   = (ln + dx) >> 1;
    }
    int rb = zw * 6 + 2 * yp;   // wave row base
    unsigned sxb = ldsoff(sx);

    u16x8 Bf[2][4][3];          // ping-pong fragment sets (asm-written)
    u16x8 Af[2][3][2];

#define DSR(dst, addr) asm volatile("ds_read_b128 %0, %1" : "=&v"(dst) : "v"(addr));

#define PFIB(ii, buf) { \
    const int dz_ = (ii) / 3, dx_ = (ii) % 3; \
    _Pragma("unroll") \
    for (int r = 0; r < 4; ++r) { \
        int rowi = rb + dz_ * 6 + r; \
        int rot = (rowi + ph[dx_]) & 3; \
        unsigned so = sxb + rowi * 3200 + pb64[dx_] + ((tq ^ rot) << 4); \
        DSR(Bf[buf][r][0], so) \
        DSR(Bf[buf][r][1], so + 1024) \
        DSR(Bf[buf][r][2], so + 2048) \
    } }

#define PFIA(ii, buf) { \
    const int dz_ = (ii) / 3, dx_ = (ii) % 3; \
    _Pragma("unroll") \
    for (int dy = 0; dy < 3; ++dy) { \
        const int tap_ = (dz_ * 3 + dy) * 3 + dx_; \
        Af[buf][dy][0] = *(const u16x8*)(aB0 + tap_ * 32); \
        Af[buf][dy][1] = *(const u16x8*)(aB1 + tap_ * 32); \
    } }

#define CMI(buf) { \
    _Pragma("unroll") \
    for (int dy = 0; dy < 3; ++dy) \
        _Pragma("unroll") \
        for (int yr = 0; yr < 2; ++yr) \
            _Pragma("unroll") \
            for (int xt = 0; xt < 3; ++xt) \
                _Pragma("unroll") \
                for (int h = 0; h < 2; ++h) \
                    acc[yr][xt][h] = __builtin_amdgcn_mfma_f32_16x16x32_bf16( \
                        __builtin_bit_cast(bf16x8, Af[buf][dy][h]), \
                        __builtin_bit_cast(bf16x8, Bf[buf][yr + dy][xt]), \
                        acc[yr][xt][h], 0, 0, 0); }

    PFIB(0, 0) PFIA(0, 0)
#pragma unroll
    for (int i = 0; i < 9; ++i) {
        if (i < 8) {
            const int nb = (i + 1) & 1;
            switch (i + 1) {    // compile-time after unroll
                case 1: PFIB(1, nb) PFIA(1, nb) break;
                case 2: PFIB(2, nb) PFIA(2, nb) break;
                case 3: PFIB(3, nb) PFIA(3, nb) break;
                case 4: PFIB(4, nb) PFIA(4, nb) break;
                case 5: PFIB(5, nb) PFIA(5, nb) break;
                case 6: PFIB(6, nb) PFIA(6, nb) break;
                case 7: PFIB(7, nb) PFIA(7, nb) break;
                case 8: PFIB(8, nb) PFIA(8, nb) break;
            }
            __builtin_amdgcn_sched_barrier(0);
            asm volatile("s_waitcnt lgkmcnt(12)");   // set i ready; 12 fly
        } else {
            asm volatile("s_waitcnt lgkmcnt(0)");    // final set
        }
        __builtin_amdgcn_sched_barrier(0);           // rule #18: fence MFMAs
        CMI(i & 1)
    }
#undef DSR
#undef PFIB
#undef PFIA
#undef CMI

    // ---- store: C layout col=lane&15 (x), row=(lane>>4)*4+reg (cout) ----
    int oz = z0 + zw;
    if (oz < 46) {
#pragma unroll
        for (int yr = 0; yr < 2; ++yr) {
            int oy = y0 + 2 * yp + yr;
            if (oy >= 46) continue;
#pragma unroll
            for (int xt = 0; xt < 3; ++xt) {
                int ox = xt * 16 + ln;
                if (ox >= 46) continue;
#pragma unroll
                for (int h = 0; h < 2; ++h) {
                    f32x4 a = acc[yr][xt][h];
#pragma unroll
                    for (int r = 0; r < 4; ++r) {
                        int co = h * 16 + tq * 4 + r;
                        out[(size_t)(b * 32 + co) * 97336 + oz * 2116 + oy * 46 + ox]
                            = a[r] + bias[co];
                    }
                }
            }
        }
    }
}

// ================= fallback path (R2, proven) ============================
__global__ __launch_bounds__(64) void wnorm16_kernel(
    const float* __restrict__ s, const float* __restrict__ sw,
    const float* __restrict__ sb, const float* __restrict__ w,
    u16* __restrict__ wA)          // [b][chunk2][cout][tap28][ci16]
{
    int bc = blockIdx.x;
    int b = bc >> 5, co = bc & 31;
    int lane = threadIdx.x;
    float s0 = s[2 * b], s1 = s[2 * b + 1];

    float sum = 0.f;
    for (int i = lane; i < 864; i += 64) {
        int ci = i / 27;
        float m = fmaf(s0, sw[2 * ci], fmaf(s1, sw[2 * ci + 1], sb[ci]));
        float v = w[co * 864 + i] * m;
        sum += v * v;
    }
#pragma unroll
    for (int off = 32; off; off >>= 1) sum += __shfl_xor(sum, off, 64);
    float rn = 1.0f / sqrtf(sum + 1e-8f);

    for (int i = lane; i < 864; i += 64) {
        int ci = i / 27, tap = i - ci * 27;
        float m = fmaf(s0, sw[2 * ci], fmaf(s1, sw[2 * ci + 1], sb[ci]));
        float v = w[co * 864 + i] * m * rn;
        int chunk = ci >> 4, ci16 = ci & 15;
        wA[(((b * 2 + chunk) * 32 + co) * 28 + tap) * 16 + ci16] = f2bf(v);
    }
    if (lane < 32) {
        int c = lane >> 4, ci16 = lane & 15;
        wA[(((b * 2 + c) * 32 + co) * 28 + 27) * 16 + ci16] = 0;
    }
}

__global__ __launch_bounds__(512) void conv_fallback(
    const float* __restrict__ xin, const u16* __restrict__ wA,
    const float* __restrict__ bias, float* __restrict__ out)
{
    __shared__ u16 sx[28800];

    int blk = blockIdx.x;
    int zt = blk % 12, yt = (blk / 12) % 12, b = blk / 144;
    int z0 = zt * 4, y0 = yt * 4;

    int t = threadIdx.x;
    int l = t & 63, w = t >> 6;
    int ln = l & 15, ch = (l >> 4) & 1, tp = l >> 5, rg = l >> 4;
    int zw = w & 3, yp = w >> 2;

    f32x4 acc[2][3][2];
#pragma unroll
    for (int i = 0; i < 2; i++)
#pragma unroll
        for (int j = 0; j < 3; j++)
#pragma unroll
            for (int h = 0; h < 2; h++) acc[i][j][h] = (f32x4)0.f;

    for (int chunk = 0; chunk < 2; ++chunk) {
        __syncthreads();
        for (int idx = t; idx < 3600; idx += 512) {
            int x = idx % 50;
            int r = idx / 50;
            int cg = r & 1; r >>= 1;
            int y = r % 6, z = r / 6;
            int gz = z0 + z, gy = y0 + y;
            bool inb = (x < 48) && (gy < 48) && (gz < 48);
            const float* xp = xin + (size_t)(b * 32 + chunk * 16 + cg * 8) * 110592
                              + gz * 2304 + gy * 48 + x;
            u16x8 v;
#pragma unroll
            for (int j = 0; j < 8; j++) {
                float f = inb ? xp[(size_t)j * 110592] : 0.f;
                v[j] = f2bf(f);
            }
            *(u16x8*)&sx[idx * 8] = v;
        }
        __syncthreads();

        const u16* wAc = wA + (b * 2 + chunk) * (32 * 28 * 16);
        int aoff = (ln * 28 + tp) * 16 + ch * 8;

#pragma unroll
        for (int s = 0; s < 14; ++s) {
            int tapA = 2 * s + tp;
            bf16x8 A0 = __builtin_bit_cast(bf16x8, *(const u16x8*)(wAc + aoff + s * 32));
            bf16x8 A1 = __builtin_bit_cast(bf16x8, *(const u16x8*)(wAc + aoff + 16 * 28 * 16 + s * 32));
            int tapB = tapA > 26 ? 26 : tapA;
            int dz = tapB / 9;
            int rr = tapB - dz * 9;
            int dy = rr / 3;
            int dx = rr - dy * 3;
            int zr = zw + dz;
#pragma unroll
            for (int yr = 0; yr < 2; ++yr) {
                int yy = 2 * yp + yr + dy;
                int eb = (((zr * 6 + yy) * 2 + ch) * 50 + ln + dx) * 8;
#pragma unroll
                for (int xt = 0; xt < 3; ++xt) {
                    bf16x8 Bf2 = __builtin_bit_cast(bf16x8, *(const u16x8*)&sx[eb + xt * 128]);
                    acc[yr][xt][0] = __builtin_amdgcn_mfma_f32_16x16x32_bf16(A0, Bf2, acc[yr][xt][0], 0, 0, 0);
                    acc[yr][xt][1] = __builtin_amdgcn_mfma_f32_16x16x32_bf16(A1, Bf2, acc[yr][xt][1], 0, 0, 0);
                }
            }
        }
    }

    int oz = z0 + zw;
    if (oz < 46) {
#pragma unroll
        for (int yr = 0; yr < 2; ++yr) {
            int oy = y0 + 2 * yp + yr;
            if (oy >= 46) continue;
#pragma unroll
            for (int xt = 0; xt < 3; ++xt) {
                int ox = xt * 16 + ln;
                if (ox >= 46) continue;
#pragma unroll
                for (int h = 0; h < 2; ++h) {
                    f32x4 a = acc[yr][xt][h];
#pragma unroll
                    for (int r = 0; r < 4; ++r) {
                        int co = h * 16 + rg * 4 + r;
                        out[(size_t)(b * 32 + co) * 97336 + oz * 2116 + oy * 46 + ox]
                            = a[r] + bias[co];
                    }
                }
            }
        }
    }
}

extern "C" void kernel_launch(void* const* d_in, const int* in_sizes, int n_in,
                              void* d_out, int out_size, void* d_ws, size_t ws_size,
                              hipStream_t stream) {
    const float* x    = (const float*)d_in[0];
    const float* s    = (const float*)d_in[1];
    const float* sw   = (const float*)d_in[2];
    const float* sb   = (const float*)d_in[3];
    const float* wgt  = (const float*)d_in[4];
    const float* bias = (const float*)d_in[5];
    float* out = (float*)d_out;

    const size_t need = (size_t)XT_BYTES + WA2_ELEMS * sizeof(u16);
    if (ws_size >= need) {
        u16* xT  = (u16*)d_ws;
        u16* wA2 = (u16*)((char*)d_ws + XT_BYTES);
        hipLaunchKernelGGL(xpose_kernel, dim3(3456), dim3(256), 0, stream, x, xT);
        hipLaunchKernelGGL(wnorm32_kernel, dim3(256), dim3(64), 0, stream,
                           s, sw, sb, wgt, wA2);
        hipLaunchKernelGGL(conv_one, dim3(12 * 12 * 8), dim3(512), 0, stream,
                           xT, wA2, bias, out);
    } else {
        u16* wA = (u16*)d_ws;
        hipLaunchKernelGGL(wnorm16_kernel, dim3(256), dim3(64), 0, stream,
                           s, sw, sb, wgt, wA);
        hipLaunchKernelGGL(conv_fallback, dim3(12 * 12 * 8), dim3(512), 0, stream,
                           x, wA, bias, out);
    }
}